// Round 8
// baseline (1887.933 us; speedup 1.0000x reference)
//
#include <hip/hip_runtime.h>
#include <hip/hip_bf16.h>

typedef __attribute__((ext_vector_type(8))) short short8v;
typedef __attribute__((ext_vector_type(4))) float float4v;
typedef unsigned int uint;
typedef unsigned short ushort;

#define EPSF 1e-5f
#define NPART 8

__device__ __forceinline__ float b2f(ushort u) {
    union { uint i; float f; } v; v.i = ((uint)u) << 16; return v.f;
}
__device__ __forceinline__ ushort f2b(float f) {
    union { float f; uint i; } v; v.f = f;
    uint r = v.i + 0x7FFF + ((v.i >> 16) & 1);
    return (ushort)(r >> 16);
}
__device__ __forceinline__ uint pack2(float lo, float hi) {
    return ((uint)f2b(hi) << 16) | (uint)f2b(lo);
}
__device__ __forceinline__ float lo16(uint u) { return b2f((ushort)(u & 0xFFFF)); }
__device__ __forceinline__ float hi16(uint u) { return b2f((ushort)(u >> 16)); }
__device__ __forceinline__ float sigm(float x) { return 1.0f / (1.0f + __expf(-x)); }

// ---------------------------------------------------------------------------
// One-time: transpose + bf16-convert the six 128x128 weight matrices.
// ---------------------------------------------------------------------------
__launch_bounds__(256)
__global__ void prep_weights(const float* __restrict__ W1, const float* __restrict__ W2,
                             const float* __restrict__ W3, const float* __restrict__ W4,
                             const float* __restrict__ Wv, const float* __restrict__ Wo,
                             ushort* __restrict__ out)
{
    __shared__ ushort Wt[128][136];
    const float* src[6] = {W1, W2, W3, W4, Wv, Wo};
    const float* W = src[blockIdx.x];
    ushort* dst = out + (size_t)blockIdx.x * 16384;
    const int tid = threadIdx.x;
    #pragma unroll
    for (int i = 0; i < 8; ++i) {
        int g = tid + i * 256;
        int k = g >> 4, o8 = (g & 15) << 3;
        float4 wa = *(const float4*)&W[k * 128 + o8];
        float4 wb = *(const float4*)&W[k * 128 + o8 + 4];
        Wt[o8 + 0][k] = f2b(wa.x); Wt[o8 + 1][k] = f2b(wa.y);
        Wt[o8 + 2][k] = f2b(wa.z); Wt[o8 + 3][k] = f2b(wa.w);
        Wt[o8 + 4][k] = f2b(wb.x); Wt[o8 + 5][k] = f2b(wb.y);
        Wt[o8 + 6][k] = f2b(wb.z); Wt[o8 + 7][k] = f2b(wb.w);
    }
    __syncthreads();
    #pragma unroll
    for (int i = 0; i < 8; ++i) {
        int g = tid + i * 256;
        int row = g >> 4, c8 = (g & 15) << 3;
        *(uint4*)&dst[row * 128 + c8] = *(const uint4*)&Wt[row][c8];
    }
}

// ---------------------------------------------------------------------------
// Combined transform (4 segments in one launch).
// ---------------------------------------------------------------------------
struct TSeg {
    const float* X; const ushort* WT; const float* bias;
    const float* aw; const float* ab;
    ushort* XJ; float* adot; int N; int blk0;
};
struct TSegs { TSeg s[4]; };

__launch_bounds__(256)
__global__ void transform4_kernel(TSegs P,
    const float* __restrict__ wq, const float* __restrict__ wqb,
    const float* __restrict__ wk, const float* __restrict__ wkb,
    float* __restrict__ qout, float* __restrict__ kout)
{
    __shared__ ushort Wt[128][136];
    __shared__ ushort Xs[64][136];
    const int tid = threadIdx.x;
    const int b = blockIdx.x;

    int seg = 3;
    if (b < P.s[1].blk0) seg = 0;
    else if (b < P.s[2].blk0) seg = 1;
    else if (b < P.s[3].blk0) seg = 2;
    const TSeg sp = P.s[seg];
    const float* __restrict__ X = sp.X;
    const int N = sp.N;
    const int rowbase = (b - sp.blk0) << 6;

    #pragma unroll
    for (int i = 0; i < 8; ++i) {
        int g = tid + i * 256;
        int row = g >> 4, c8 = (g & 15) << 3;
        *(uint4*)&Wt[row][c8] = *(const uint4*)&sp.WT[row * 128 + c8];
    }
    #pragma unroll
    for (int i = 0; i < 4; ++i) {
        int g = tid + i * 256;
        int r = g >> 4;
        int c8 = (g & 15) << 3;
        int grow = rowbase + r;
        uint4 v = make_uint4(0, 0, 0, 0);
        if (grow < N) {
            float4 xa = *(const float4*)&X[(size_t)grow * 128 + c8];
            float4 xb = *(const float4*)&X[(size_t)grow * 128 + c8 + 4];
            v.x = pack2(xa.x, xa.y); v.y = pack2(xa.z, xa.w);
            v.z = pack2(xb.x, xb.y); v.w = pack2(xb.z, xb.w);
        }
        *(uint4*)&Xs[r][c8] = v;
    }
    __syncthreads();

    const int wv = tid >> 6, lane = tid & 63;
    const int c = lane & 15, blk = lane >> 4;

    float4v acc[8];
    #pragma unroll
    for (int n = 0; n < 8; ++n) acc[n] = (float4v){0.f, 0.f, 0.f, 0.f};

    #pragma unroll
    for (int kk = 0; kk < 4; ++kk) {
        short8v a = *(const short8v*)&Xs[wv * 16 + c][kk * 32 + blk * 8];
        #pragma unroll
        for (int n = 0; n < 8; ++n) {
            short8v bb = *(const short8v*)&Wt[n * 16 + c][kk * 32 + blk * 8];
            acc[n] = __builtin_amdgcn_mfma_f32_16x16x32_bf16(a, bb, acc[n], 0, 0, 0);
        }
    }

    float ad[4] = {0.f, 0.f, 0.f, 0.f};
    #pragma unroll
    for (int n = 0; n < 8; ++n) {
        int col = n * 16 + c;
        float bc = sp.bias[col];
        float ac = sp.aw[col];
        #pragma unroll
        for (int i = 0; i < 4; ++i) {
            float v = acc[n][i] + bc;
            v = (v >= 0.f) ? v : 0.2f * v;       // leaky 0.2
            ad[i] += v * ac;
            if (sp.XJ) {
                int grow = rowbase + wv * 16 + blk * 4 + i;
                if (grow < N) sp.XJ[(size_t)grow * 128 + col] = f2b(v);
            }
        }
    }
    #pragma unroll
    for (int m = 1; m < 16; m <<= 1)
        #pragma unroll
        for (int i = 0; i < 4; ++i) ad[i] += __shfl_xor(ad[i], m);
    if (c == 0) {
        float abv = sp.ab[0];
        #pragma unroll
        for (int i = 0; i < 4; ++i) {
            int grow = rowbase + wv * 16 + blk * 4 + i;
            if (grow < N) sp.adot[grow] = ad[i] + abv;
        }
    }

    if (seg == 0) {   // q = X@wq + wqb, k = X@wk + wkb on raw f32 X
        float wq0 = wq[2 * lane], wq1 = wq[2 * lane + 1];
        float wk0 = wk[2 * lane], wk1 = wk[2 * lane + 1];
        float qb = wqb[0], kb = wkb[0];
        for (int i = 0; i < 16; ++i) {
            int r = wv * 16 + i;
            int grow = rowbase + r;
            float x0v = 0.f, x1v = 0.f;
            if (grow < N) {
                float2 xx = *(const float2*)&X[(size_t)grow * 128 + 2 * lane];
                x0v = xx.x; x1v = xx.y;
            }
            float qp = x0v * wq0 + x1v * wq1;
            float kp = x0v * wk0 + x1v * wk1;
            #pragma unroll
            for (int m = 1; m < 64; m <<= 1) {
                qp += __shfl_xor(qp, m);
                kp += __shfl_xor(kp, m);
            }
            if (lane == 0 && grow < N) { qout[grow] = qp + qb; kout[grow] = kp + kb; }
        }
    }
}

// ---------------------------------------------------------------------------
// Binning: append 4B entry ((row&127)<<17 | col) into per-128-row-bucket
// lists. Partitioned by XCD (p = blockIdx.x & 7 owns rows [p*N0/8,...)) so
// each partition's ~1.5MB bucket region + cursors stay L2-resident.
// ---------------------------------------------------------------------------
__launch_bounds__(256)
__global__ void bin_kernel(const int* __restrict__ r0, const int* __restrict__ r1,
                           const int* __restrict__ r2,
                           const int* __restrict__ c0, const int* __restrict__ c1,
                           const int* __restrict__ c2,
                           int E, int N0, int nchunk, int NB0, int CAP,
                           int* __restrict__ bcnt, uint* __restrict__ bins)
{
    const int p = blockIdx.x & (NPART - 1);
    const int cb = blockIdx.x / NPART;
    const int prange = (N0 + NPART - 1) / NPART;
    const int rlo = p * prange, rhi = min(N0, rlo + prange);
    const int per = (E + nchunk - 1) / nchunk;
    const int lo = cb * per, hi = min(E, lo + per);
    const int* rs[3] = {r0, r1, r2};
    const int* cs[3] = {c0, c1, c2};
    for (int s = 0; s < 3; ++s) {
        const int* __restrict__ r = rs[s];
        const int* __restrict__ c = cs[s];
        int* __restrict__ bc = bcnt + s * NB0;
        uint* __restrict__ bs = bins + (size_t)s * NB0 * CAP;
        for (int e = lo + threadIdx.x; e < hi; e += 256) {
            int rr = r[e];
            if (rr < rlo || rr >= rhi) continue;
            int bkt = rr >> 7;
            int pos = atomicAdd(&bc[bkt], 1);
            if (pos < CAP)
                bs[(size_t)bkt * CAP + pos] = ((uint)(rr & 127) << 17) | (uint)c[e];
        }
    }
}

// ---------------------------------------------------------------------------
// Bucket aggregation: one 512-thread block per (set, 128-row bucket).
// f32 accumulate in 64KB LDS via atomicAdd (swizzled: col 2l -> [l],
// col 2l+1 -> [l+64] => conflict-free banks). Epilogue: bf16 agg + kvals dot.
// ---------------------------------------------------------------------------
__launch_bounds__(512)
__global__ void aggbin_kernel(const ushort* __restrict__ xj0, const ushort* __restrict__ xj1,
                              const ushort* __restrict__ xj2,
                              const float* __restrict__ ai0,
                              const float* __restrict__ aj0, const float* __restrict__ aj1,
                              const float* __restrict__ aj2,
                              const uint* __restrict__ bins, const int* __restrict__ bcnt,
                              int N0, int NB0, int CAP,
                              const float* __restrict__ wk, const float* __restrict__ wkb,
                              ushort* __restrict__ agg, float* __restrict__ kvals)
{
    __shared__ float lds[128][128];        // 64 KB exactly
    const int b = blockIdx.x;
    const int s = b / NB0;
    const int bi = b - s * NB0;
    const int rowbase = bi << 7;
    const ushort* __restrict__ xj = (s == 0) ? xj0 : ((s == 1) ? xj1 : xj2);
    const float* __restrict__ aj = (s == 0) ? aj0 : ((s == 1) ? aj1 : aj2);
    const float* __restrict__ ai = ai0 + rowbase;
    const int tid = threadIdx.x;
    const int lane = tid & 63, wv = tid >> 6;   // 8 waves

    // zero LDS: 16384 f32 / 512 threads = 32 each
    float4 z = make_float4(0.f, 0.f, 0.f, 0.f);
    float* lf = &lds[0][0];
    #pragma unroll
    for (int i = 0; i < 8; ++i)
        *(float4*)&lf[tid * 4 + i * 2048] = z;
    __syncthreads();

    int cnt = min(bcnt[b], CAP);
    const uint* __restrict__ bb = bins + (size_t)b * CAP;

    for (int j = wv; j < cnt; j += 16) {
        int jB = j + 8;
        uint enA = bb[j];
        int rlA = enA >> 17, colA = enA & 0x1FFFF;
        bool hasB = (jB < cnt);
        uint enB = hasB ? bb[jB] : 0;
        int rlB = enB >> 17, colB = enB & 0x1FFFF;
        uint pxA = *(const uint*)&xj[(size_t)colA * 128 + lane * 2];
        uint pxB = *(const uint*)&xj[(size_t)colB * 128 + lane * 2];
        float sgA = sigm(ai[rlA] + aj[colA]);
        atomicAdd(&lds[rlA][lane], sgA * lo16(pxA));
        atomicAdd(&lds[rlA][lane + 64], sgA * hi16(pxA));
        if (hasB) {
            float sgB = sigm(ai[rlB] + aj[colB]);
            atomicAdd(&lds[rlB][lane], sgB * lo16(pxB));
            atomicAdd(&lds[rlB][lane + 64], sgB * hi16(pxB));
        }
    }
    __syncthreads();

    float wk0 = wk[2 * lane], wk1 = wk[2 * lane + 1], kb = wkb[0];
    for (int r = wv; r < 128; r += 8) {
        int gr = rowbase + r;
        if (gr >= N0) break;
        float v0 = lds[r][lane], v1 = lds[r][lane + 64];
        *(uint*)&agg[((size_t)s * N0 + gr) * 128 + 2 * lane] = pack2(v0, v1);
        float kp = v0 * wk0 + v1 * wk1;
        #pragma unroll
        for (int m = 1; m < 64; m <<= 1) kp += __shfl_xor(kp, m);
        if (lane == 0) kvals[s * N0 + gr] = kp + kb;
    }
}

// ---------------------------------------------------------------------------
// Fused mix + GEMM(wvwT) + LN1 -> bf16
// ---------------------------------------------------------------------------
__launch_bounds__(256)
__global__ void mixln_kernel(const float* __restrict__ x0, int N,
    const ushort* __restrict__ aggAll,
    const float* __restrict__ q, const float* __restrict__ kx0,
    const float* __restrict__ kvals,
    const ushort* __restrict__ WT, const float* __restrict__ bvec,
    const float* __restrict__ g, const float* __restrict__ beta,
    ushort* __restrict__ out)
{
    __shared__ ushort Wt[128][136];
    __shared__ ushort Xs[64][136];
    __shared__ float4 srow[64];
    const int tid = threadIdx.x;
    const int N0 = N;

    #pragma unroll
    for (int i = 0; i < 8; ++i) {
        int gi = tid + i * 256;
        int row = gi >> 4, c8 = (gi & 15) << 3;
        *(uint4*)&Wt[row][c8] = *(const uint4*)&WT[row * 128 + c8];
    }
    const int rowbase = blockIdx.x << 6;
    if (tid < 64) {
        int row = rowbase + tid;
        float4 sv = make_float4(0.f, 0.f, 0.f, 0.f);
        if (row < N) {
            float qv = q[row];
            sv.x = sigm(qv * kx0[row]);
            sv.y = sigm(qv * kvals[row]);
            sv.z = sigm(qv * kvals[N0 + row]);
            sv.w = sigm(qv * kvals[2 * N0 + row]);
        }
        srow[tid] = sv;
    }
    __syncthreads();

    #pragma unroll
    for (int i = 0; i < 4; ++i) {
        int gi = tid + i * 256;
        int r = gi >> 4;
        int c8 = (gi & 15) << 3;
        int grow = rowbase + r;
        uint4 v = make_uint4(0, 0, 0, 0);
        if (grow < N) {
            float4 sv = srow[r];
            float4 xa = *(const float4*)&x0[(size_t)grow * 128 + c8];
            float4 xb = *(const float4*)&x0[(size_t)grow * 128 + c8 + 4];
            uint4 g0 = *(const uint4*)&aggAll[(size_t)grow * 128 + c8];
            uint4 g1 = *(const uint4*)&aggAll[((size_t)N0 + grow) * 128 + c8];
            uint4 g2 = *(const uint4*)&aggAll[((size_t)2 * N0 + grow) * 128 + c8];
            float t0 = sv.x * xa.x + sv.y * lo16(g0.x) + sv.z * lo16(g1.x) + sv.w * lo16(g2.x);
            float t1 = sv.x * xa.y + sv.y * hi16(g0.x) + sv.z * hi16(g1.x) + sv.w * hi16(g2.x);
            float t2 = sv.x * xa.z + sv.y * lo16(g0.y) + sv.z * lo16(g1.y) + sv.w * lo16(g2.y);
            float t3 = sv.x * xa.w + sv.y * hi16(g0.y) + sv.z * hi16(g1.y) + sv.w * hi16(g2.y);
            float t4 = sv.x * xb.x + sv.y * lo16(g0.z) + sv.z * lo16(g1.z) + sv.w * lo16(g2.z);
            float t5 = sv.x * xb.y + sv.y * hi16(g0.z) + sv.z * hi16(g1.z) + sv.w * hi16(g2.z);
            float t6 = sv.x * xb.z + sv.y * lo16(g0.w) + sv.z * lo16(g1.w) + sv.w * lo16(g2.w);
            float t7 = sv.x * xb.w + sv.y * hi16(g0.w) + sv.z * hi16(g1.w) + sv.w * hi16(g2.w);
            v.x = pack2(t0, t1); v.y = pack2(t2, t3);
            v.z = pack2(t4, t5); v.w = pack2(t6, t7);
        }
        *(uint4*)&Xs[r][c8] = v;
    }
    __syncthreads();

    const int wv = tid >> 6, lane = tid & 63;
    const int c = lane & 15, blk = lane >> 4;

    float4v acc[8];
    #pragma unroll
    for (int n = 0; n < 8; ++n) acc[n] = (float4v){0.f, 0.f, 0.f, 0.f};
    #pragma unroll
    for (int kk = 0; kk < 4; ++kk) {
        short8v a = *(const short8v*)&Xs[wv * 16 + c][kk * 32 + blk * 8];
        #pragma unroll
        for (int n = 0; n < 8; ++n) {
            short8v bb = *(const short8v*)&Wt[n * 16 + c][kk * 32 + blk * 8];
            acc[n] = __builtin_amdgcn_mfma_f32_16x16x32_bf16(a, bb, acc[n], 0, 0, 0);
        }
    }

    float cf[4];
    #pragma unroll
    for (int i = 0; i < 4; ++i) {
        int rloc = wv * 16 + blk * 4 + i;
        float4 sv = srow[rloc];
        cf[i] = (sv.x + sv.y + sv.z + sv.w) * 0.25f;
    }

    float vals[8][4];
    float sum[4] = {0.f, 0.f, 0.f, 0.f}, sq[4] = {0.f, 0.f, 0.f, 0.f};
    #pragma unroll
    for (int n = 0; n < 8; ++n) {
        int col = n * 16 + c;
        float bc = bvec[col];
        #pragma unroll
        for (int i = 0; i < 4; ++i) {
            int grow = rowbase + wv * 16 + blk * 4 + i;
            float rv = (grow < N) ? x0[(size_t)grow * 128 + col] : 0.f;
            float v = acc[n][i] * 0.25f + cf[i] * bc + rv;
            vals[n][i] = v;
            sum[i] += v;
            sq[i] += v * v;
        }
    }
    #pragma unroll
    for (int m = 1; m < 16; m <<= 1)
        #pragma unroll
        for (int i = 0; i < 4; ++i) {
            sum[i] += __shfl_xor(sum[i], m);
            sq[i] += __shfl_xor(sq[i], m);
        }
    float mu[4], rs[4];
    #pragma unroll
    for (int i = 0; i < 4; ++i) {
        mu[i] = sum[i] * (1.0f / 128.0f);
        float var = sq[i] * (1.0f / 128.0f) - mu[i] * mu[i];
        rs[i] = rsqrtf(var + EPSF);
    }
    #pragma unroll
    for (int n = 0; n < 8; ++n) {
        int col = n * 16 + c;
        float gc = g[col], bc = beta[col];
        #pragma unroll
        for (int i = 0; i < 4; ++i) {
            int grow = rowbase + wv * 16 + blk * 4 + i;
            if (grow < N)
                out[(size_t)grow * 128 + col] = f2b((vals[n][i] - mu[i]) * rs[i] * gc + bc);
        }
    }
}

// ---------------------------------------------------------------------------
// Final: y = A@Wo + bo + A; out = LN(y) -> f32
// ---------------------------------------------------------------------------
__launch_bounds__(256)
__global__ void gemm_ln_kernel(const ushort* __restrict__ A, int N,
    const ushort* __restrict__ WT, const float* __restrict__ bvec,
    const float* __restrict__ g, const float* __restrict__ beta,
    float* __restrict__ outF)
{
    __shared__ ushort Wt[128][136];
    __shared__ ushort Xs[64][136];
    const int tid = threadIdx.x;

    #pragma unroll
    for (int i = 0; i < 8; ++i) {
        int gi = tid + i * 256;
        int row = gi >> 4, c8 = (gi & 15) << 3;
        *(uint4*)&Wt[row][c8] = *(const uint4*)&WT[row * 128 + c8];
    }
    const int rowbase = blockIdx.x << 6;
    #pragma unroll
    for (int i = 0; i < 4; ++i) {
        int gi = tid + i * 256;
        int r = gi >> 4;
        int c8 = (gi & 15) << 3;
        int grow = rowbase + r;
        uint4 v = make_uint4(0, 0, 0, 0);
        if (grow < N) v = *(const uint4*)&A[(size_t)grow * 128 + c8];
        *(uint4*)&Xs[r][c8] = v;
    }
    __syncthreads();

    const int wv = tid >> 6, lane = tid & 63;
    const int c = lane & 15, blk = lane >> 4;

    float4v acc[8];
    #pragma unroll
    for (int n = 0; n < 8; ++n) acc[n] = (float4v){0.f, 0.f, 0.f, 0.f};
    #pragma unroll
    for (int kk = 0; kk < 4; ++kk) {
        short8v a = *(const short8v*)&Xs[wv * 16 + c][kk * 32 + blk * 8];
        #pragma unroll
        for (int n = 0; n < 8; ++n) {
            short8v bb = *(const short8v*)&Wt[n * 16 + c][kk * 32 + blk * 8];
            acc[n] = __builtin_amdgcn_mfma_f32_16x16x32_bf16(a, bb, acc[n], 0, 0, 0);
        }
    }

    float vals[8][4];
    float sum[4] = {0.f, 0.f, 0.f, 0.f}, sq[4] = {0.f, 0.f, 0.f, 0.f};
    #pragma unroll
    for (int n = 0; n < 8; ++n) {
        int col = n * 16 + c;
        float bc = bvec[col];
        #pragma unroll
        for (int i = 0; i < 4; ++i) {
            int rloc = wv * 16 + blk * 4 + i;
            float rv = b2f(Xs[rloc][col]);   // resid = A (bf16) from LDS
            float v = acc[n][i] + bc + rv;
            vals[n][i] = v;
            sum[i] += v;
            sq[i] += v * v;
        }
    }
    #pragma unroll
    for (int m = 1; m < 16; m <<= 1)
        #pragma unroll
        for (int i = 0; i < 4; ++i) {
            sum[i] += __shfl_xor(sum[i], m);
            sq[i] += __shfl_xor(sq[i], m);
        }
    float mu[4], rs[4];
    #pragma unroll
    for (int i = 0; i < 4; ++i) {
        mu[i] = sum[i] * (1.0f / 128.0f);
        float var = sq[i] * (1.0f / 128.0f) - mu[i] * mu[i];
        rs[i] = rsqrtf(var + EPSF);
    }
    #pragma unroll
    for (int n = 0; n < 8; ++n) {
        int col = n * 16 + c;
        float gc = g[col], bc = beta[col];
        #pragma unroll
        for (int i = 0; i < 4; ++i) {
            int grow = rowbase + wv * 16 + blk * 4 + i;
            if (grow < N)
                outF[(size_t)grow * 128 + col] = (vals[n][i] - mu[i]) * rs[i] * gc + bc;
        }
    }
}

// ---------------------------------------------------------------------------
extern "C" void kernel_launch(void* const* d_in, const int* in_sizes, int n_in,
                              void* d_out, int out_size, void* d_ws, size_t ws_size,
                              hipStream_t stream)
{
    const float* x0 = (const float*)d_in[0];
    const float* x1 = (const float*)d_in[1];
    const float* x2 = (const float*)d_in[2];
    const int* rows0 = (const int*)d_in[3];
    const int* cols0 = (const int*)d_in[4];
    const int* rows1 = (const int*)d_in[5];
    const int* cols1 = (const int*)d_in[6];
    const int* rows2 = (const int*)d_in[7];
    const int* cols2 = (const int*)d_in[8];
    const float* W1 = (const float*)d_in[9];   const float* b1 = (const float*)d_in[10];
    const float* W2 = (const float*)d_in[11];  const float* b2 = (const float*)d_in[12];
    const float* W3 = (const float*)d_in[13];  const float* b3 = (const float*)d_in[14];
    const float* W4 = (const float*)d_in[15];  const float* b4 = (const float*)d_in[16];
    const float* a1w = (const float*)d_in[17]; const float* a1b = (const float*)d_in[18];
    const float* a2w = (const float*)d_in[19]; const float* a2b = (const float*)d_in[20];
    const float* a3w = (const float*)d_in[21]; const float* a3b = (const float*)d_in[22];
    const float* a4w = (const float*)d_in[23]; const float* a4b = (const float*)d_in[24];
    const float* wqw = (const float*)d_in[25]; const float* wqb = (const float*)d_in[26];
    const float* wkw = (const float*)d_in[27]; const float* wkb = (const float*)d_in[28];
    const float* wvw = (const float*)d_in[29]; const float* wvb = (const float*)d_in[30];
    const float* Wo  = (const float*)d_in[31]; const float* bo = (const float*)d_in[32];
    const float* ln1g = (const float*)d_in[33]; const float* ln1b = (const float*)d_in[34];
    const float* ln2g = (const float*)d_in[35]; const float* ln2b = (const float*)d_in[36];

    const int N0 = in_sizes[0] / 128;
    const int N1 = in_sizes[1] / 128;
    const int N2 = in_sizes[2] / 128;
    const int E  = in_sizes[3];
    const int NB0 = (N0 + 127) >> 7;              // 128-row buckets per set
    const int CAP = ((2 * E / NB0) + 63) & ~63;   // 2x mean, safe margin

    char* p = (char*)d_ws;
    auto walloc = [&](size_t bytes) -> void* {
        void* r = (void*)p;
        p += (bytes + 255) & ~(size_t)255;
        return r;
    };
    ushort* agg  = (ushort*)walloc((size_t)3 * N0 * 128 * 2);
    ushort* xj0  = (ushort*)walloc((size_t)N0 * 128 * 2);
    ushort* xj1  = (ushort*)walloc((size_t)N1 * 128 * 2);
    ushort* xj2  = (ushort*)walloc((size_t)N2 * 128 * 2);
    float* ai0   = (float*)walloc((size_t)N0 * 4);
    float* aj0   = (float*)walloc((size_t)N0 * 4);
    float* aj1   = (float*)walloc((size_t)N1 * 4);
    float* aj2   = (float*)walloc((size_t)N2 * 4);
    float* qv    = (float*)walloc((size_t)N0 * 4);
    float* kx0   = (float*)walloc((size_t)N0 * 4);
    float* kvals = (float*)walloc((size_t)3 * N0 * 4);
    int* bcnt    = (int*)walloc((size_t)3 * NB0 * 4);
    ushort* wtb  = (ushort*)walloc((size_t)6 * 16384 * 2);   // 6 transposed bf16 weights
    uint* bins   = (uint*)walloc((size_t)3 * NB0 * CAP * 4);
    ushort* u = (N1 >= N0) ? xj1 : (ushort*)walloc((size_t)N0 * 128 * 2);

    hipMemsetAsync(bcnt, 0, (size_t)3 * NB0 * 4, stream);

    // one-time weight transpose+convert
    prep_weights<<<6, 256, 0, stream>>>(W1, W2, W3, W4, wvw, Wo, wtb);
    const ushort* W1T = wtb;
    const ushort* W2T = wtb + 16384;
    const ushort* W3T = wtb + 2 * 16384;
    const ushort* W4T = wtb + 3 * 16384;
    const ushort* WvT = wtb + 4 * 16384;
    const ushort* WoT = wtb + 5 * 16384;

    // combined transforms (one launch)
    int nb0 = (N0 + 63) / 64, nb1 = (N1 + 63) / 64, nb2 = (N2 + 63) / 64;
    TSegs P;
    P.s[0] = {x0, W1T, b1, a1w, a1b, nullptr, ai0, N0, 0};
    P.s[1] = {x0, W2T, b2, a2w, a2b, xj0, aj0, N0, nb0};
    P.s[2] = {x1, W3T, b3, a3w, a3b, xj1, aj1, N1, 2 * nb0};
    P.s[3] = {x2, W4T, b4, a4w, a4b, xj2, aj2, N2, 2 * nb0 + nb1};
    transform4_kernel<<<2 * nb0 + nb1 + nb2, 256, 0, stream>>>(
        P, wqw, wqb, wkw, wkb, qv, kx0);

    // binning (XCD-partitioned append, 4B entries)
    const int nchunk = 120;
    bin_kernel<<<NPART * nchunk, 256, 0, stream>>>(rows0, rows1, rows2,
                                                   cols0, cols1, cols2,
                                                   E, N0, nchunk, NB0, CAP, bcnt, bins);

    // bucket aggregation (LDS f32 accumulate)
    aggbin_kernel<<<3 * NB0, 512, 0, stream>>>(
        xj0, xj1, xj2, ai0, aj0, aj1, aj2, bins, bcnt, N0, NB0, CAP,
        wkw, wkb, agg, kvals);

    // fused mix + GEMM(wvw) + LN1 -> u (bf16)
    mixln_kernel<<<(N0 + 63) / 64, 256, 0, stream>>>(
        x0, N0, agg, qv, kx0, kvals, WvT, wvb, ln1g, ln1b, u);

    // u@Wo + bo + u -> LN2 -> out (f32)
    gemm_ln_kernel<<<(N0 + 63) / 64, 256, 0, stream>>>(
        u, N0, WoT, bo, ln2g, ln2b, (float*)d_out);
}

// Round 9
// 355.934 us; speedup vs baseline: 5.3042x; 5.3042x over previous
//
#include <hip/hip_runtime.h>
#include <hip/hip_bf16.h>

typedef __attribute__((ext_vector_type(8))) short short8v;
typedef __attribute__((ext_vector_type(4))) float float4v;
typedef unsigned int uint;
typedef unsigned short ushort;

#define EPSF 1e-5f
#define NPART 8

__device__ __forceinline__ float b2f(ushort u) {
    union { uint i; float f; } v; v.i = ((uint)u) << 16; return v.f;
}
__device__ __forceinline__ ushort f2b(float f) {
    union { float f; uint i; } v; v.f = f;
    uint r = v.i + 0x7FFF + ((v.i >> 16) & 1);
    return (ushort)(r >> 16);
}
__device__ __forceinline__ uint pack2(float lo, float hi) {
    return ((uint)f2b(hi) << 16) | (uint)f2b(lo);
}
__device__ __forceinline__ float lo16(uint u) { return b2f((ushort)(u & 0xFFFF)); }
__device__ __forceinline__ float hi16(uint u) { return b2f((ushort)(u >> 16)); }
__device__ __forceinline__ float sigm(float x) { return 1.0f / (1.0f + __expf(-x)); }

__device__ __forceinline__ int wave_incl_scan(int x, int lane) {
    #pragma unroll
    for (int d = 1; d < 64; d <<= 1) {
        int v = __shfl_up(x, d);
        if (lane >= d) x += v;
    }
    return x;
}

// ---------------------------------------------------------------------------
// One-time: transpose + bf16-convert the six 128x128 weight matrices.
// ---------------------------------------------------------------------------
__launch_bounds__(256)
__global__ void prep_weights(const float* __restrict__ W1, const float* __restrict__ W2,
                             const float* __restrict__ W3, const float* __restrict__ W4,
                             const float* __restrict__ Wv, const float* __restrict__ Wo,
                             ushort* __restrict__ out)
{
    __shared__ ushort Wt[128][136];
    const float* src[6] = {W1, W2, W3, W4, Wv, Wo};
    const float* W = src[blockIdx.x];
    ushort* dst = out + (size_t)blockIdx.x * 16384;
    const int tid = threadIdx.x;
    #pragma unroll
    for (int i = 0; i < 8; ++i) {
        int g = tid + i * 256;
        int k = g >> 4, o8 = (g & 15) << 3;
        float4 wa = *(const float4*)&W[k * 128 + o8];
        float4 wb = *(const float4*)&W[k * 128 + o8 + 4];
        Wt[o8 + 0][k] = f2b(wa.x); Wt[o8 + 1][k] = f2b(wa.y);
        Wt[o8 + 2][k] = f2b(wa.z); Wt[o8 + 3][k] = f2b(wa.w);
        Wt[o8 + 4][k] = f2b(wb.x); Wt[o8 + 5][k] = f2b(wb.y);
        Wt[o8 + 6][k] = f2b(wb.z); Wt[o8 + 7][k] = f2b(wb.w);
    }
    __syncthreads();
    #pragma unroll
    for (int i = 0; i < 8; ++i) {
        int g = tid + i * 256;
        int row = g >> 4, c8 = (g & 15) << 3;
        *(uint4*)&dst[row * 128 + c8] = *(const uint4*)&Wt[row][c8];
    }
}

// ---------------------------------------------------------------------------
// Combined transform (4 segments in one launch).
// ---------------------------------------------------------------------------
struct TSeg {
    const float* X; const ushort* WT; const float* bias;
    const float* aw; const float* ab;
    ushort* XJ; float* adot; int N; int blk0;
};
struct TSegs { TSeg s[4]; };

__launch_bounds__(256)
__global__ void transform4_kernel(TSegs P,
    const float* __restrict__ wq, const float* __restrict__ wqb,
    const float* __restrict__ wk, const float* __restrict__ wkb,
    float* __restrict__ qout, float* __restrict__ kout)
{
    __shared__ ushort Wt[128][136];
    __shared__ ushort Xs[64][136];
    const int tid = threadIdx.x;
    const int b = blockIdx.x;

    int seg = 3;
    if (b < P.s[1].blk0) seg = 0;
    else if (b < P.s[2].blk0) seg = 1;
    else if (b < P.s[3].blk0) seg = 2;
    const TSeg sp = P.s[seg];
    const float* __restrict__ X = sp.X;
    const int N = sp.N;
    const int rowbase = (b - sp.blk0) << 6;

    #pragma unroll
    for (int i = 0; i < 8; ++i) {
        int g = tid + i * 256;
        int row = g >> 4, c8 = (g & 15) << 3;
        *(uint4*)&Wt[row][c8] = *(const uint4*)&sp.WT[row * 128 + c8];
    }
    #pragma unroll
    for (int i = 0; i < 4; ++i) {
        int g = tid + i * 256;
        int r = g >> 4;
        int c8 = (g & 15) << 3;
        int grow = rowbase + r;
        uint4 v = make_uint4(0, 0, 0, 0);
        if (grow < N) {
            float4 xa = *(const float4*)&X[(size_t)grow * 128 + c8];
            float4 xb = *(const float4*)&X[(size_t)grow * 128 + c8 + 4];
            v.x = pack2(xa.x, xa.y); v.y = pack2(xa.z, xa.w);
            v.z = pack2(xb.x, xb.y); v.w = pack2(xb.z, xb.w);
        }
        *(uint4*)&Xs[r][c8] = v;
    }
    __syncthreads();

    const int wv = tid >> 6, lane = tid & 63;
    const int c = lane & 15, blk = lane >> 4;

    float4v acc[8];
    #pragma unroll
    for (int n = 0; n < 8; ++n) acc[n] = (float4v){0.f, 0.f, 0.f, 0.f};

    #pragma unroll
    for (int kk = 0; kk < 4; ++kk) {
        short8v a = *(const short8v*)&Xs[wv * 16 + c][kk * 32 + blk * 8];
        #pragma unroll
        for (int n = 0; n < 8; ++n) {
            short8v bb = *(const short8v*)&Wt[n * 16 + c][kk * 32 + blk * 8];
            acc[n] = __builtin_amdgcn_mfma_f32_16x16x32_bf16(a, bb, acc[n], 0, 0, 0);
        }
    }

    float ad[4] = {0.f, 0.f, 0.f, 0.f};
    #pragma unroll
    for (int n = 0; n < 8; ++n) {
        int col = n * 16 + c;
        float bc = sp.bias[col];
        float ac = sp.aw[col];
        #pragma unroll
        for (int i = 0; i < 4; ++i) {
            float v = acc[n][i] + bc;
            v = (v >= 0.f) ? v : 0.2f * v;       // leaky 0.2
            ad[i] += v * ac;
            if (sp.XJ) {
                int grow = rowbase + wv * 16 + blk * 4 + i;
                if (grow < N) sp.XJ[(size_t)grow * 128 + col] = f2b(v);
            }
        }
    }
    #pragma unroll
    for (int m = 1; m < 16; m <<= 1)
        #pragma unroll
        for (int i = 0; i < 4; ++i) ad[i] += __shfl_xor(ad[i], m);
    if (c == 0) {
        float abv = sp.ab[0];
        #pragma unroll
        for (int i = 0; i < 4; ++i) {
            int grow = rowbase + wv * 16 + blk * 4 + i;
            if (grow < N) sp.adot[grow] = ad[i] + abv;
        }
    }

    if (seg == 0) {   // q = X@wq + wqb, k = X@wk + wkb on raw f32 X
        float wq0 = wq[2 * lane], wq1 = wq[2 * lane + 1];
        float wk0 = wk[2 * lane], wk1 = wk[2 * lane + 1];
        float qb = wqb[0], kb = wkb[0];
        for (int i = 0; i < 16; ++i) {
            int r = wv * 16 + i;
            int grow = rowbase + r;
            float x0v = 0.f, x1v = 0.f;
            if (grow < N) {
                float2 xx = *(const float2*)&X[(size_t)grow * 128 + 2 * lane];
                x0v = xx.x; x1v = xx.y;
            }
            float qp = x0v * wq0 + x1v * wq1;
            float kp = x0v * wk0 + x1v * wk1;
            #pragma unroll
            for (int m = 1; m < 64; m <<= 1) {
                qp += __shfl_xor(qp, m);
                kp += __shfl_xor(kp, m);
            }
            if (lane == 0 && grow < N) { qout[grow] = qp + qb; kout[grow] = kp + kb; }
        }
    }
}

// ---------------------------------------------------------------------------
// CSR build — XCD-local partitioned scatter. Streaming reads (rows/cols) use
// NON-TEMPORAL loads so they don't evict the scatter region's dirty L2 lines
// (R7 showed the 50MB read stream churning the 4MB L2 was the residual
// write-amplification source).
// ---------------------------------------------------------------------------
__launch_bounds__(256)
__global__ void degree_kernel(const int* __restrict__ r0, const int* __restrict__ r1,
                              const int* __restrict__ r2, int E, int N0, int nchunk,
                              int* __restrict__ deg)
{
    const int p = blockIdx.x & (NPART - 1);
    const int cb = blockIdx.x / NPART;
    const int prange = (N0 + NPART - 1) / NPART;
    const int rlo = p * prange, rhi = min(N0, rlo + prange);
    const int per = (E + nchunk - 1) / nchunk;
    const int lo = cb * per, hi = min(E, lo + per);
    const int* rs[3] = {r0, r1, r2};
    for (int s = 0; s < 3; ++s) {
        const int* __restrict__ r = rs[s];
        int* __restrict__ dg = deg + s * N0;
        for (int e = lo + threadIdx.x; e < hi; e += 256) {
            int rr = __builtin_nontemporal_load(&r[e]);
            if (rr >= rlo && rr < rhi) atomicAdd(&dg[rr], 1);
        }
    }
}

__launch_bounds__(256)
__global__ void scan_phase1(const int* __restrict__ deg, int M, int* __restrict__ bsum)
{
    int base = blockIdx.x * 1024 + threadIdx.x * 4;
    int s = 0;
    if (base + 3 < M) {
        int4 v = *(const int4*)&deg[base];
        s = v.x + v.y + v.z + v.w;
    } else {
        for (int i = 0; i < 4; ++i) if (base + i < M) s += deg[base + i];
    }
    int lane = threadIdx.x & 63, wv = threadIdx.x >> 6;
    #pragma unroll
    for (int m = 1; m < 64; m <<= 1) s += __shfl_xor(s, m);
    __shared__ int ws[4];
    if (lane == 0) ws[wv] = s;
    __syncthreads();
    if (threadIdx.x == 0) bsum[blockIdx.x] = ws[0] + ws[1] + ws[2] + ws[3];
}

__launch_bounds__(1024)
__global__ void scan_phase2(int* __restrict__ bsum, int B, int M, int* __restrict__ offs)
{
    int t = threadIdx.x;
    int v = (t < B) ? bsum[t] : 0;
    int lane = t & 63, wv = t >> 6;
    int incl = wave_incl_scan(v, lane);
    __shared__ int ws[16];
    if (lane == 63) ws[wv] = incl;
    __syncthreads();
    int add = 0;
    for (int i = 0; i < wv; ++i) add += ws[i];
    incl += add;
    if (t < B) bsum[t] = incl - v;      // exclusive block offsets
    if (t == 1023) offs[M] = incl;      // grand total
}

__launch_bounds__(256)
__global__ void scan_phase3(const int* __restrict__ deg, int M,
                            const int* __restrict__ bsum,
                            int* __restrict__ offs, int* __restrict__ cursor)
{
    int base = blockIdx.x * 1024 + threadIdx.x * 4;
    int4 v = make_int4(0, 0, 0, 0);
    bool full = (base + 3 < M);
    if (full) v = *(const int4*)&deg[base];
    else {
        if (base + 0 < M) v.x = deg[base + 0];
        if (base + 1 < M) v.y = deg[base + 1];
        if (base + 2 < M) v.z = deg[base + 2];
    }
    int s = v.x + v.y + v.z + v.w;
    int lane = threadIdx.x & 63, wv = threadIdx.x >> 6;
    int incl = wave_incl_scan(s, lane);
    __shared__ int ws[4];
    if (lane == 63) ws[wv] = incl;
    __syncthreads();
    int add = bsum[blockIdx.x];
    for (int i = 0; i < wv; ++i) add += ws[i];
    int o0 = add + incl - s;
    int o1 = o0 + v.x, o2 = o1 + v.y, o3 = o2 + v.z;
    if (full) {
        *(int4*)&offs[base]   = make_int4(o0, o1, o2, o3);
        *(int4*)&cursor[base] = make_int4(o0, o1, o2, o3);
    } else {
        int ov[4] = {o0, o1, o2, o3};
        for (int i = 0; i < 4; ++i)
            if (base + i < M) { offs[base + i] = ov[i]; cursor[base + i] = ov[i]; }
    }
}

// fill (partitioned, NT streaming reads): stores (col, sigmoid) per edge in
// CSR order. Partition-local cursors + elist region stay L2-resident.
__launch_bounds__(256)
__global__ void fill_kernel(const int* __restrict__ r0, const int* __restrict__ r1,
                            const int* __restrict__ r2,
                            const int* __restrict__ c0, const int* __restrict__ c1,
                            const int* __restrict__ c2, int E, int N0, int nchunk,
                            const float* __restrict__ ai0,
                            const float* __restrict__ aj0,
                            const float* __restrict__ aj1,
                            const float* __restrict__ aj2,
                            int* __restrict__ cursor, uint2* __restrict__ elist2)
{
    const int p = blockIdx.x & (NPART - 1);
    const int cb = blockIdx.x / NPART;
    const int prange = (N0 + NPART - 1) / NPART;
    const int rlo = p * prange, rhi = min(N0, rlo + prange);
    const int per = (E + nchunk - 1) / nchunk;
    const int lo = cb * per, hi = min(E, lo + per);
    const int* rs[3] = {r0, r1, r2};
    const int* cs[3] = {c0, c1, c2};
    const float* as[3] = {aj0, aj1, aj2};
    for (int s = 0; s < 3; ++s) {
        const int* __restrict__ r = rs[s];
        const int* __restrict__ c = cs[s];
        const float* __restrict__ aj = as[s];
        int* __restrict__ cur = cursor + s * N0;
        for (int e = lo + threadIdx.x; e < hi; e += 256) {
            int rr = __builtin_nontemporal_load(&r[e]);
            if (rr < rlo || rr >= rhi) continue;
            int col = __builtin_nontemporal_load(&c[e]);
            float sg = sigm(ai0[rr] + aj[col]);
            int pos = atomicAdd(&cur[rr], 1);
            uint2 v; v.x = (uint)col; v.y = __float_as_uint(sg);
            elist2[pos] = v;
        }
    }
}

// ---------------------------------------------------------------------------
// Aggregation: one wave per (set s, row r); 8 edges in flight per iteration
// (quarter-wave per edge x 2-deep unroll; each lane gathers 16B of the row).
// Fused: kvals[s][r] = agg[s][r] . wk + wkb
// ---------------------------------------------------------------------------
__launch_bounds__(256)
__global__ void agg_kernel(const ushort* __restrict__ xj0, const ushort* __restrict__ xj1,
                           const ushort* __restrict__ xj2,
                           const int* __restrict__ offs, const uint2* __restrict__ elist2,
                           const float* __restrict__ wk, const float* __restrict__ wkb,
                           int N0,
                           ushort* __restrict__ agg, float* __restrict__ kvals)
{
    int w = (blockIdx.x * blockDim.x + threadIdx.x) >> 6;
    int lane = threadIdx.x & 63;
    if (w >= 3 * N0) return;
    int s = w / N0;
    const ushort* xj = (s == 0) ? xj0 : ((s == 1) ? xj1 : xj2);

    int q = lane >> 4;         // quarter 0..3
    int ql = lane & 15;        // 16B chunk of row

    int beg = offs[w], end = offs[w + 1];
    float a0 = 0.f, a1 = 0.f, a2 = 0.f, a3 = 0.f;
    float a4 = 0.f, a5 = 0.f, a6 = 0.f, a7 = 0.f;
    for (int j = beg; j < end; j += 8) {
        int jA = j + q;
        int jB = j + 4 + q;
        int colA = 0, colB = 0;
        float sgA = 0.f, sgB = 0.f;
        if (jA < end) {
            uint2 es = elist2[jA];
            colA = (int)es.x; sgA = __uint_as_float(es.y);
        }
        if (jB < end) {
            uint2 es = elist2[jB];
            colB = (int)es.x; sgB = __uint_as_float(es.y);
        }
        uint4 pA = *(const uint4*)&xj[(size_t)colA * 128 + ql * 8];
        uint4 pB = *(const uint4*)&xj[(size_t)colB * 128 + ql * 8];
        a0 += sgA * lo16(pA.x); a1 += sgA * hi16(pA.x);
        a2 += sgA * lo16(pA.y); a3 += sgA * hi16(pA.y);
        a4 += sgA * lo16(pA.z); a5 += sgA * hi16(pA.z);
        a6 += sgA * lo16(pA.w); a7 += sgA * hi16(pA.w);
        a0 += sgB * lo16(pB.x); a1 += sgB * hi16(pB.x);
        a2 += sgB * lo16(pB.y); a3 += sgB * hi16(pB.y);
        a4 += sgB * lo16(pB.z); a5 += sgB * hi16(pB.z);
        a6 += sgB * lo16(pB.w); a7 += sgB * hi16(pB.w);
    }
    // combine the four quarters
    a0 += __shfl_xor(a0, 16); a0 += __shfl_xor(a0, 32);
    a1 += __shfl_xor(a1, 16); a1 += __shfl_xor(a1, 32);
    a2 += __shfl_xor(a2, 16); a2 += __shfl_xor(a2, 32);
    a3 += __shfl_xor(a3, 16); a3 += __shfl_xor(a3, 32);
    a4 += __shfl_xor(a4, 16); a4 += __shfl_xor(a4, 32);
    a5 += __shfl_xor(a5, 16); a5 += __shfl_xor(a5, 32);
    a6 += __shfl_xor(a6, 16); a6 += __shfl_xor(a6, 32);
    a7 += __shfl_xor(a7, 16); a7 += __shfl_xor(a7, 32);

    if (q == 0) {
        uint4 o;
        o.x = pack2(a0, a1); o.y = pack2(a2, a3);
        o.z = pack2(a4, a5); o.w = pack2(a6, a7);
        *(uint4*)&agg[(size_t)w * 128 + ql * 8] = o;
    }

    float4 wka = *(const float4*)&wk[ql * 8];
    float4 wkb4 = *(const float4*)&wk[ql * 8 + 4];
    float kp = a0 * wka.x + a1 * wka.y + a2 * wka.z + a3 * wka.w
             + a4 * wkb4.x + a5 * wkb4.y + a6 * wkb4.z + a7 * wkb4.w;
    #pragma unroll
    for (int m = 1; m < 16; m <<= 1) kp += __shfl_xor(kp, m);
    if (lane == 0) kvals[w] = kp + wkb[0];
}

// ---------------------------------------------------------------------------
// Fused mix + GEMM(wvwT) + LN1 -> bf16
// ---------------------------------------------------------------------------
__launch_bounds__(256)
__global__ void mixln_kernel(const float* __restrict__ x0, int N,
    const ushort* __restrict__ aggAll,
    const float* __restrict__ q, const float* __restrict__ kx0,
    const float* __restrict__ kvals,
    const ushort* __restrict__ WT, const float* __restrict__ bvec,
    const float* __restrict__ g, const float* __restrict__ beta,
    ushort* __restrict__ out)
{
    __shared__ ushort Wt[128][136];
    __shared__ ushort Xs[64][136];
    __shared__ float4 srow[64];
    const int tid = threadIdx.x;
    const int N0 = N;

    #pragma unroll
    for (int i = 0; i < 8; ++i) {
        int gi = tid + i * 256;
        int row = gi >> 4, c8 = (gi & 15) << 3;
        *(uint4*)&Wt[row][c8] = *(const uint4*)&WT[row * 128 + c8];
    }
    const int rowbase = blockIdx.x << 6;
    if (tid < 64) {
        int row = rowbase + tid;
        float4 sv = make_float4(0.f, 0.f, 0.f, 0.f);
        if (row < N) {
            float qv = q[row];
            sv.x = sigm(qv * kx0[row]);
            sv.y = sigm(qv * kvals[row]);
            sv.z = sigm(qv * kvals[N0 + row]);
            sv.w = sigm(qv * kvals[2 * N0 + row]);
        }
        srow[tid] = sv;
    }
    __syncthreads();

    #pragma unroll
    for (int i = 0; i < 4; ++i) {
        int gi = tid + i * 256;
        int r = gi >> 4;
        int c8 = (gi & 15) << 3;
        int grow = rowbase + r;
        uint4 v = make_uint4(0, 0, 0, 0);
        if (grow < N) {
            float4 sv = srow[r];
            float4 xa = *(const float4*)&x0[(size_t)grow * 128 + c8];
            float4 xb = *(const float4*)&x0[(size_t)grow * 128 + c8 + 4];
            uint4 g0 = *(const uint4*)&aggAll[(size_t)grow * 128 + c8];
            uint4 g1 = *(const uint4*)&aggAll[((size_t)N0 + grow) * 128 + c8];
            uint4 g2 = *(const uint4*)&aggAll[((size_t)2 * N0 + grow) * 128 + c8];
            float t0 = sv.x * xa.x + sv.y * lo16(g0.x) + sv.z * lo16(g1.x) + sv.w * lo16(g2.x);
            float t1 = sv.x * xa.y + sv.y * hi16(g0.x) + sv.z * hi16(g1.x) + sv.w * hi16(g2.x);
            float t2 = sv.x * xa.z + sv.y * lo16(g0.y) + sv.z * lo16(g1.y) + sv.w * lo16(g2.y);
            float t3 = sv.x * xa.w + sv.y * hi16(g0.y) + sv.z * hi16(g1.y) + sv.w * hi16(g2.y);
            float t4 = sv.x * xb.x + sv.y * lo16(g0.z) + sv.z * lo16(g1.z) + sv.w * lo16(g2.z);
            float t5 = sv.x * xb.y + sv.y * hi16(g0.z) + sv.z * hi16(g1.z) + sv.w * hi16(g2.z);
            float t6 = sv.x * xb.z + sv.y * lo16(g0.w) + sv.z * lo16(g1.w) + sv.w * lo16(g2.w);
            float t7 = sv.x * xb.w + sv.y * hi16(g0.w) + sv.z * hi16(g1.w) + sv.w * hi16(g2.w);
            v.x = pack2(t0, t1); v.y = pack2(t2, t3);
            v.z = pack2(t4, t5); v.w = pack2(t6, t7);
        }
        *(uint4*)&Xs[r][c8] = v;
    }
    __syncthreads();

    const int wv = tid >> 6, lane = tid & 63;
    const int c = lane & 15, blk = lane >> 4;

    float4v acc[8];
    #pragma unroll
    for (int n = 0; n < 8; ++n) acc[n] = (float4v){0.f, 0.f, 0.f, 0.f};
    #pragma unroll
    for (int kk = 0; kk < 4; ++kk) {
        short8v a = *(const short8v*)&Xs[wv * 16 + c][kk * 32 + blk * 8];
        #pragma unroll
        for (int n = 0; n < 8; ++n) {
            short8v bb = *(const short8v*)&Wt[n * 16 + c][kk * 32 + blk * 8];
            acc[n] = __builtin_amdgcn_mfma_f32_16x16x32_bf16(a, bb, acc[n], 0, 0, 0);
        }
    }

    float cf[4];
    #pragma unroll
    for (int i = 0; i < 4; ++i) {
        int rloc = wv * 16 + blk * 4 + i;
        float4 sv = srow[rloc];
        cf[i] = (sv.x + sv.y + sv.z + sv.w) * 0.25f;
    }

    float vals[8][4];
    float sum[4] = {0.f, 0.f, 0.f, 0.f}, sq[4] = {0.f, 0.f, 0.f, 0.f};
    #pragma unroll
    for (int n = 0; n < 8; ++n) {
        int col = n * 16 + c;
        float bc = bvec[col];
        #pragma unroll
        for (int i = 0; i < 4; ++i) {
            int grow = rowbase + wv * 16 + blk * 4 + i;
            float rv = (grow < N) ? x0[(size_t)grow * 128 + col] : 0.f;
            float v = acc[n][i] * 0.25f + cf[i] * bc + rv;
            vals[n][i] = v;
            sum[i] += v;
            sq[i] += v * v;
        }
    }
    #pragma unroll
    for (int m = 1; m < 16; m <<= 1)
        #pragma unroll
        for (int i = 0; i < 4; ++i) {
            sum[i] += __shfl_xor(sum[i], m);
            sq[i] += __shfl_xor(sq[i], m);
        }
    float mu[4], rs[4];
    #pragma unroll
    for (int i = 0; i < 4; ++i) {
        mu[i] = sum[i] * (1.0f / 128.0f);
        float var = sq[i] * (1.0f / 128.0f) - mu[i] * mu[i];
        rs[i] = rsqrtf(var + EPSF);
    }
    #pragma unroll
    for (int n = 0; n < 8; ++n) {
        int col = n * 16 + c;
        float gc = g[col], bc = beta[col];
        #pragma unroll
        for (int i = 0; i < 4; ++i) {
            int grow = rowbase + wv * 16 + blk * 4 + i;
            if (grow < N)
                out[(size_t)grow * 128 + col] = f2b((vals[n][i] - mu[i]) * rs[i] * gc + bc);
        }
    }
}

// ---------------------------------------------------------------------------
// Final: y = A@Wo + bo + A; out = LN(y) -> f32
// ---------------------------------------------------------------------------
__launch_bounds__(256)
__global__ void gemm_ln_kernel(const ushort* __restrict__ A, int N,
    const ushort* __restrict__ WT, const float* __restrict__ bvec,
    const float* __restrict__ g, const float* __restrict__ beta,
    float* __restrict__ outF)
{
    __shared__ ushort Wt[128][136];
    __shared__ ushort Xs[64][136];
    const int tid = threadIdx.x;

    #pragma unroll
    for (int i = 0; i < 8; ++i) {
        int gi = tid + i * 256;
        int row = gi >> 4, c8 = (gi & 15) << 3;
        *(uint4*)&Wt[row][c8] = *(const uint4*)&WT[row * 128 + c8];
    }
    const int rowbase = blockIdx.x << 6;
    #pragma unroll
    for (int i = 0; i < 4; ++i) {
        int gi = tid + i * 256;
        int r = gi >> 4;
        int c8 = (gi & 15) << 3;
        int grow = rowbase + r;
        uint4 v = make_uint4(0, 0, 0, 0);
        if (grow < N) v = *(const uint4*)&A[(size_t)grow * 128 + c8];
        *(uint4*)&Xs[r][c8] = v;
    }
    __syncthreads();

    const int wv = tid >> 6, lane = tid & 63;
    const int c = lane & 15, blk = lane >> 4;

    float4v acc[8];
    #pragma unroll
    for (int n = 0; n < 8; ++n) acc[n] = (float4v){0.f, 0.f, 0.f, 0.f};
    #pragma unroll
    for (int kk = 0; kk < 4; ++kk) {
        short8v a = *(const short8v*)&Xs[wv * 16 + c][kk * 32 + blk * 8];
        #pragma unroll
        for (int n = 0; n < 8; ++n) {
            short8v bb = *(const short8v*)&Wt[n * 16 + c][kk * 32 + blk * 8];
            acc[n] = __builtin_amdgcn_mfma_f32_16x16x32_bf16(a, bb, acc[n], 0, 0, 0);
        }
    }

    float vals[8][4];
    float sum[4] = {0.f, 0.f, 0.f, 0.f}, sq[4] = {0.f, 0.f, 0.f, 0.f};
    #pragma unroll
    for (int n = 0; n < 8; ++n) {
        int col = n * 16 + c;
        float bc = bvec[col];
        #pragma unroll
        for (int i = 0; i < 4; ++i) {
            int rloc = wv * 16 + blk * 4 + i;
            float rv = b2f(Xs[rloc][col]);   // resid = A (bf16) from LDS
            float v = acc[n][i] + bc + rv;
            vals[n][i] = v;
            sum[i] += v;
            sq[i] += v * v;
        }
    }
    #pragma unroll
    for (int m = 1; m < 16; m <<= 1)
        #pragma unroll
        for (int i = 0; i < 4; ++i) {
            sum[i] += __shfl_xor(sum[i], m);
            sq[i] += __shfl_xor(sq[i], m);
        }
    float mu[4], rs[4];
    #pragma unroll
    for (int i = 0; i < 4; ++i) {
        mu[i] = sum[i] * (1.0f / 128.0f);
        float var = sq[i] * (1.0f / 128.0f) - mu[i] * mu[i];
        rs[i] = rsqrtf(var + EPSF);
    }
    #pragma unroll
    for (int n = 0; n < 8; ++n) {
        int col = n * 16 + c;
        float gc = g[col], bc = beta[col];
        #pragma unroll
        for (int i = 0; i < 4; ++i) {
            int grow = rowbase + wv * 16 + blk * 4 + i;
            if (grow < N)
                outF[(size_t)grow * 128 + col] = (vals[n][i] - mu[i]) * rs[i] * gc + bc;
        }
    }
}

// ---------------------------------------------------------------------------
extern "C" void kernel_launch(void* const* d_in, const int* in_sizes, int n_in,
                              void* d_out, int out_size, void* d_ws, size_t ws_size,
                              hipStream_t stream)
{
    const float* x0 = (const float*)d_in[0];
    const float* x1 = (const float*)d_in[1];
    const float* x2 = (const float*)d_in[2];
    const int* rows0 = (const int*)d_in[3];
    const int* cols0 = (const int*)d_in[4];
    const int* rows1 = (const int*)d_in[5];
    const int* cols1 = (const int*)d_in[6];
    const int* rows2 = (const int*)d_in[7];
    const int* cols2 = (const int*)d_in[8];
    const float* W1 = (const float*)d_in[9];   const float* b1 = (const float*)d_in[10];
    const float* W2 = (const float*)d_in[11];  const float* b2 = (const float*)d_in[12];
    const float* W3 = (const float*)d_in[13];  const float* b3 = (const float*)d_in[14];
    const float* W4 = (const float*)d_in[15];  const float* b4 = (const float*)d_in[16];
    const float* a1w = (const float*)d_in[17]; const float* a1b = (const float*)d_in[18];
    const float* a2w = (const float*)d_in[19]; const float* a2b = (const float*)d_in[20];
    const float* a3w = (const float*)d_in[21]; const float* a3b = (const float*)d_in[22];
    const float* a4w = (const float*)d_in[23]; const float* a4b = (const float*)d_in[24];
    const float* wqw = (const float*)d_in[25]; const float* wqb = (const float*)d_in[26];
    const float* wkw = (const float*)d_in[27]; const float* wkb = (const float*)d_in[28];
    const float* wvw = (const float*)d_in[29]; const float* wvb = (const float*)d_in[30];
    const float* Wo  = (const float*)d_in[31]; const float* bo = (const float*)d_in[32];
    const float* ln1g = (const float*)d_in[33]; const float* ln1b = (const float*)d_in[34];
    const float* ln2g = (const float*)d_in[35]; const float* ln2b = (const float*)d_in[36];

    const int N0 = in_sizes[0] / 128;
    const int N1 = in_sizes[1] / 128;
    const int N2 = in_sizes[2] / 128;
    const int E  = in_sizes[3];
    const int M  = 3 * N0;

    char* p = (char*)d_ws;
    auto walloc = [&](size_t bytes) -> void* {
        void* r = (void*)p;
        p += (bytes + 255) & ~(size_t)255;
        return r;
    };
    ushort* agg  = (ushort*)walloc((size_t)3 * N0 * 128 * 2);
    ushort* xj0  = (ushort*)walloc((size_t)N0 * 128 * 2);
    ushort* xj1  = (ushort*)walloc((size_t)N1 * 128 * 2);
    ushort* xj2  = (ushort*)walloc((size_t)N2 * 128 * 2);
    float* ai0   = (float*)walloc((size_t)N0 * 4);
    float* aj0   = (float*)walloc((size_t)N0 * 4);
    float* aj1   = (float*)walloc((size_t)N1 * 4);
    float* aj2   = (float*)walloc((size_t)N2 * 4);
    float* qv    = (float*)walloc((size_t)N0 * 4);
    float* kx0   = (float*)walloc((size_t)N0 * 4);
    float* kvals = (float*)walloc((size_t)3 * N0 * 4);
    int* deg     = (int*)walloc((size_t)M * 4);
    int* offs    = (int*)walloc(((size_t)M + 1) * 4);
    int* cursor  = (int*)walloc((size_t)M * 4);
    int* bsum    = (int*)walloc(1024 * 4);
    ushort* wtb  = (ushort*)walloc((size_t)6 * 16384 * 2);   // 6 transposed bf16 weights
    uint2* elist2 = (uint2*)walloc((size_t)3 * E * 8);
    ushort* u = (N1 >= N0) ? xj1 : (ushort*)walloc((size_t)N0 * 128 * 2);

    hipMemsetAsync(deg, 0, (size_t)M * 4, stream);

    // one-time weight transpose+convert
    prep_weights<<<6, 256, 0, stream>>>(W1, W2, W3, W4, wvw, Wo, wtb);
    const ushort* W1T = wtb;
    const ushort* W2T = wtb + 16384;
    const ushort* W3T = wtb + 2 * 16384;
    const ushort* W4T = wtb + 3 * 16384;
    const ushort* WvT = wtb + 4 * 16384;
    const ushort* WoT = wtb + 5 * 16384;

    // combined transforms (one launch)
    int nb0 = (N0 + 63) / 64, nb1 = (N1 + 63) / 64, nb2 = (N2 + 63) / 64;
    TSegs P;
    P.s[0] = {x0, W1T, b1, a1w, a1b, nullptr, ai0, N0, 0};
    P.s[1] = {x0, W2T, b2, a2w, a2b, xj0, aj0, N0, nb0};
    P.s[2] = {x1, W3T, b3, a3w, a3b, xj1, aj1, N1, 2 * nb0};
    P.s[3] = {x2, W4T, b4, a4w, a4b, xj2, aj2, N2, 2 * nb0 + nb1};
    transform4_kernel<<<2 * nb0 + nb1 + nb2, 256, 0, stream>>>(
        P, wqw, wqb, wkw, wkb, qv, kx0);

    // CSR build — XCD-local partitioned scatter, NT streaming reads
    const int nchunk = 120;                         // blocks per partition
    degree_kernel<<<NPART * nchunk, 256, 0, stream>>>(rows0, rows1, rows2, E, N0,
                                                      nchunk, deg);
    int nb = (M + 1023) / 1024;
    scan_phase1<<<nb, 256, 0, stream>>>(deg, M, bsum);
    scan_phase2<<<1, 1024, 0, stream>>>(bsum, nb, M, offs);
    scan_phase3<<<nb, 256, 0, stream>>>(deg, M, bsum, offs, cursor);
    fill_kernel<<<NPART * nchunk, 256, 0, stream>>>(rows0, rows1, rows2,
                                                    cols0, cols1, cols2, E, N0, nchunk,
                                                    ai0, aj0, aj1, aj2, cursor, elist2);

    // aggregation (one wave per (s,row), 8 edges in flight)
    int aggblocks = (3 * N0 + 3) / 4;
    agg_kernel<<<aggblocks, 256, 0, stream>>>(
        xj0, xj1, xj2, offs, elist2, wkw, wkb, N0, agg, kvals);

    // fused mix + GEMM(wvw) + LN1 -> u (bf16)
    mixln_kernel<<<(N0 + 63) / 64, 256, 0, stream>>>(
        x0, N0, agg, qv, kx0, kvals, WvT, wvb, ln1g, ln1b, u);

    // u@Wo + bo + u -> LN2 -> out (f32)
    gemm_ln_kernel<<<(N0 + 63) / 64, 256, 0, stream>>>(
        u, N0, WoT, bo, ln2g, ln2b, (float*)d_out);
}

// Round 10
// 326.576 us; speedup vs baseline: 5.7810x; 1.0899x over previous
//
#include <hip/hip_runtime.h>
#include <hip/hip_bf16.h>

typedef __attribute__((ext_vector_type(8))) short short8v;
typedef __attribute__((ext_vector_type(4))) float float4v;
typedef unsigned int uint;
typedef unsigned short ushort;

#define EPSF 1e-5f
#define NPART 8

__device__ __forceinline__ float b2f(ushort u) {
    union { uint i; float f; } v; v.i = ((uint)u) << 16; return v.f;
}
__device__ __forceinline__ ushort f2b(float f) {
    union { float f; uint i; } v; v.f = f;
    uint r = v.i + 0x7FFF + ((v.i >> 16) & 1);
    return (ushort)(r >> 16);
}
__device__ __forceinline__ uint pack2(float lo, float hi) {
    return ((uint)f2b(hi) << 16) | (uint)f2b(lo);
}
__device__ __forceinline__ float lo16(uint u) { return b2f((ushort)(u & 0xFFFF)); }
__device__ __forceinline__ float hi16(uint u) { return b2f((ushort)(u >> 16)); }
__device__ __forceinline__ float sigm(float x) { return 1.0f / (1.0f + __expf(-x)); }

__device__ __forceinline__ int wave_incl_scan(int x, int lane) {
    #pragma unroll
    for (int d = 1; d < 64; d <<= 1) {
        int v = __shfl_up(x, d);
        if (lane >= d) x += v;
    }
    return x;
}

// ---------------------------------------------------------------------------
// One-time: transpose + bf16-convert the six 128x128 weight matrices.
// ---------------------------------------------------------------------------
__launch_bounds__(256)
__global__ void prep_weights(const float* __restrict__ W1, const float* __restrict__ W2,
                             const float* __restrict__ W3, const float* __restrict__ W4,
                             const float* __restrict__ Wv, const float* __restrict__ Wo,
                             ushort* __restrict__ out)
{
    __shared__ ushort Wt[128][136];
    const float* src[6] = {W1, W2, W3, W4, Wv, Wo};
    const float* W = src[blockIdx.x];
    ushort* dst = out + (size_t)blockIdx.x * 16384;
    const int tid = threadIdx.x;
    #pragma unroll
    for (int i = 0; i < 8; ++i) {
        int g = tid + i * 256;
        int k = g >> 4, o8 = (g & 15) << 3;
        float4 wa = *(const float4*)&W[k * 128 + o8];
        float4 wb = *(const float4*)&W[k * 128 + o8 + 4];
        Wt[o8 + 0][k] = f2b(wa.x); Wt[o8 + 1][k] = f2b(wa.y);
        Wt[o8 + 2][k] = f2b(wa.z); Wt[o8 + 3][k] = f2b(wa.w);
        Wt[o8 + 4][k] = f2b(wb.x); Wt[o8 + 5][k] = f2b(wb.y);
        Wt[o8 + 6][k] = f2b(wb.z); Wt[o8 + 7][k] = f2b(wb.w);
    }
    __syncthreads();
    #pragma unroll
    for (int i = 0; i < 8; ++i) {
        int g = tid + i * 256;
        int row = g >> 4, c8 = (g & 15) << 3;
        *(uint4*)&dst[row * 128 + c8] = *(const uint4*)&Wt[row][c8];
    }
}

// ---------------------------------------------------------------------------
// Combined transform (4 segments in one launch).
// ---------------------------------------------------------------------------
struct TSeg {
    const float* X; const ushort* WT; const float* bias;
    const float* aw; const float* ab;
    ushort* XJ; float* adot; int N; int blk0;
};
struct TSegs { TSeg s[4]; };

__launch_bounds__(256)
__global__ void transform4_kernel(TSegs P,
    const float* __restrict__ wq, const float* __restrict__ wqb,
    const float* __restrict__ wk, const float* __restrict__ wkb,
    float* __restrict__ qout, float* __restrict__ kout)
{
    __shared__ ushort Wt[128][136];
    __shared__ ushort Xs[64][136];
    const int tid = threadIdx.x;
    const int b = blockIdx.x;

    int seg = 3;
    if (b < P.s[1].blk0) seg = 0;
    else if (b < P.s[2].blk0) seg = 1;
    else if (b < P.s[3].blk0) seg = 2;
    const TSeg sp = P.s[seg];
    const float* __restrict__ X = sp.X;
    const int N = sp.N;
    const int rowbase = (b - sp.blk0) << 6;

    #pragma unroll
    for (int i = 0; i < 8; ++i) {
        int g = tid + i * 256;
        int row = g >> 4, c8 = (g & 15) << 3;
        *(uint4*)&Wt[row][c8] = *(const uint4*)&sp.WT[row * 128 + c8];
    }
    #pragma unroll
    for (int i = 0; i < 4; ++i) {
        int g = tid + i * 256;
        int r = g >> 4;
        int c8 = (g & 15) << 3;
        int grow = rowbase + r;
        uint4 v = make_uint4(0, 0, 0, 0);
        if (grow < N) {
            float4 xa = *(const float4*)&X[(size_t)grow * 128 + c8];
            float4 xb = *(const float4*)&X[(size_t)grow * 128 + c8 + 4];
            v.x = pack2(xa.x, xa.y); v.y = pack2(xa.z, xa.w);
            v.z = pack2(xb.x, xb.y); v.w = pack2(xb.z, xb.w);
        }
        *(uint4*)&Xs[r][c8] = v;
    }
    __syncthreads();

    const int wv = tid >> 6, lane = tid & 63;
    const int c = lane & 15, blk = lane >> 4;

    float4v acc[8];
    #pragma unroll
    for (int n = 0; n < 8; ++n) acc[n] = (float4v){0.f, 0.f, 0.f, 0.f};

    #pragma unroll
    for (int kk = 0; kk < 4; ++kk) {
        short8v a = *(const short8v*)&Xs[wv * 16 + c][kk * 32 + blk * 8];
        #pragma unroll
        for (int n = 0; n < 8; ++n) {
            short8v bb = *(const short8v*)&Wt[n * 16 + c][kk * 32 + blk * 8];
            acc[n] = __builtin_amdgcn_mfma_f32_16x16x32_bf16(a, bb, acc[n], 0, 0, 0);
        }
    }

    float ad[4] = {0.f, 0.f, 0.f, 0.f};
    #pragma unroll
    for (int n = 0; n < 8; ++n) {
        int col = n * 16 + c;
        float bc = sp.bias[col];
        float ac = sp.aw[col];
        #pragma unroll
        for (int i = 0; i < 4; ++i) {
            float v = acc[n][i] + bc;
            v = (v >= 0.f) ? v : 0.2f * v;       // leaky 0.2
            ad[i] += v * ac;
            if (sp.XJ) {
                int grow = rowbase + wv * 16 + blk * 4 + i;
                if (grow < N) sp.XJ[(size_t)grow * 128 + col] = f2b(v);
            }
        }
    }
    #pragma unroll
    for (int m = 1; m < 16; m <<= 1)
        #pragma unroll
        for (int i = 0; i < 4; ++i) ad[i] += __shfl_xor(ad[i], m);
    if (c == 0) {
        float abv = sp.ab[0];
        #pragma unroll
        for (int i = 0; i < 4; ++i) {
            int grow = rowbase + wv * 16 + blk * 4 + i;
            if (grow < N) sp.adot[grow] = ad[i] + abv;
        }
    }

    if (seg == 0) {   // q = X@wq + wqb, k = X@wk + wkb on raw f32 X
        float wq0 = wq[2 * lane], wq1 = wq[2 * lane + 1];
        float wk0 = wk[2 * lane], wk1 = wk[2 * lane + 1];
        float qb = wqb[0], kb = wkb[0];
        for (int i = 0; i < 16; ++i) {
            int r = wv * 16 + i;
            int grow = rowbase + r;
            float x0v = 0.f, x1v = 0.f;
            if (grow < N) {
                float2 xx = *(const float2*)&X[(size_t)grow * 128 + 2 * lane];
                x0v = xx.x; x1v = xx.y;
            }
            float qp = x0v * wq0 + x1v * wq1;
            float kp = x0v * wk0 + x1v * wk1;
            #pragma unroll
            for (int m = 1; m < 64; m <<= 1) {
                qp += __shfl_xor(qp, m);
                kp += __shfl_xor(kp, m);
            }
            if (lane == 0 && grow < N) { qout[grow] = qp + qb; kout[grow] = kp + kb; }
        }
    }
}

// ---------------------------------------------------------------------------
// CSR build — XCD-local partitioned scatter, HIGH-OCCUPANCY grid (latency-
// bound kernels: R9 showed 37% occupancy from too few blocks was the cap).
// ---------------------------------------------------------------------------
__launch_bounds__(256)
__global__ void degree_kernel(const int* __restrict__ r0, const int* __restrict__ r1,
                              const int* __restrict__ r2, int E, int N0, int nchunk,
                              int* __restrict__ deg)
{
    const int p = blockIdx.x & (NPART - 1);
    const int cb = blockIdx.x / NPART;
    const int prange = (N0 + NPART - 1) / NPART;
    const int rlo = p * prange, rhi = min(N0, rlo + prange);
    const int per = (E + nchunk - 1) / nchunk;
    const int lo = cb * per, hi = min(E, lo + per);
    const int* rs[3] = {r0, r1, r2};
    for (int s = 0; s < 3; ++s) {
        const int* __restrict__ r = rs[s];
        int* __restrict__ dg = deg + s * N0;
        for (int e = lo + threadIdx.x; e < hi; e += 256) {
            int rr = r[e];
            if (rr >= rlo && rr < rhi) atomicAdd(&dg[rr], 1);
        }
    }
}

__launch_bounds__(256)
__global__ void scan_phase1(const int* __restrict__ deg, int M, int* __restrict__ bsum)
{
    int base = blockIdx.x * 1024 + threadIdx.x * 4;
    int s = 0;
    if (base + 3 < M) {
        int4 v = *(const int4*)&deg[base];
        s = v.x + v.y + v.z + v.w;
    } else {
        for (int i = 0; i < 4; ++i) if (base + i < M) s += deg[base + i];
    }
    int lane = threadIdx.x & 63, wv = threadIdx.x >> 6;
    #pragma unroll
    for (int m = 1; m < 64; m <<= 1) s += __shfl_xor(s, m);
    __shared__ int ws[4];
    if (lane == 0) ws[wv] = s;
    __syncthreads();
    if (threadIdx.x == 0) bsum[blockIdx.x] = ws[0] + ws[1] + ws[2] + ws[3];
}

__launch_bounds__(1024)
__global__ void scan_phase2(int* __restrict__ bsum, int B, int M, int* __restrict__ offs)
{
    int t = threadIdx.x;
    int v = (t < B) ? bsum[t] : 0;
    int lane = t & 63, wv = t >> 6;
    int incl = wave_incl_scan(v, lane);
    __shared__ int ws[16];
    if (lane == 63) ws[wv] = incl;
    __syncthreads();
    int add = 0;
    for (int i = 0; i < wv; ++i) add += ws[i];
    incl += add;
    if (t < B) bsum[t] = incl - v;      // exclusive block offsets
    if (t == 1023) offs[M] = incl;      // grand total
}

__launch_bounds__(256)
__global__ void scan_phase3(const int* __restrict__ deg, int M,
                            const int* __restrict__ bsum,
                            int* __restrict__ offs, int* __restrict__ cursor)
{
    int base = blockIdx.x * 1024 + threadIdx.x * 4;
    int4 v = make_int4(0, 0, 0, 0);
    bool full = (base + 3 < M);
    if (full) v = *(const int4*)&deg[base];
    else {
        if (base + 0 < M) v.x = deg[base + 0];
        if (base + 1 < M) v.y = deg[base + 1];
        if (base + 2 < M) v.z = deg[base + 2];
    }
    int s = v.x + v.y + v.z + v.w;
    int lane = threadIdx.x & 63, wv = threadIdx.x >> 6;
    int incl = wave_incl_scan(s, lane);
    __shared__ int ws[4];
    if (lane == 63) ws[wv] = incl;
    __syncthreads();
    int add = bsum[blockIdx.x];
    for (int i = 0; i < wv; ++i) add += ws[i];
    int o0 = add + incl - s;
    int o1 = o0 + v.x, o2 = o1 + v.y, o3 = o2 + v.z;
    if (full) {
        *(int4*)&offs[base]   = make_int4(o0, o1, o2, o3);
        *(int4*)&cursor[base] = make_int4(o0, o1, o2, o3);
    } else {
        int ov[4] = {o0, o1, o2, o3};
        for (int i = 0; i < 4; ++i)
            if (base + i < M) { offs[base + i] = ov[i]; cursor[base + i] = ov[i]; }
    }
}

// fill (partitioned, high-occupancy): stores (col, sigmoid) per edge in CSR
// order. Partition-local cursors + elist region stay L2-resident.
__launch_bounds__(256)
__global__ void fill_kernel(const int* __restrict__ r0, const int* __restrict__ r1,
                            const int* __restrict__ r2,
                            const int* __restrict__ c0, const int* __restrict__ c1,
                            const int* __restrict__ c2, int E, int N0, int nchunk,
                            const float* __restrict__ ai0,
                            const float* __restrict__ aj0,
                            const float* __restrict__ aj1,
                            const float* __restrict__ aj2,
                            int* __restrict__ cursor, uint2* __restrict__ elist2)
{
    const int p = blockIdx.x & (NPART - 1);
    const int cb = blockIdx.x / NPART;
    const int prange = (N0 + NPART - 1) / NPART;
    const int rlo = p * prange, rhi = min(N0, rlo + prange);
    const int per = (E + nchunk - 1) / nchunk;
    const int lo = cb * per, hi = min(E, lo + per);
    const int* rs[3] = {r0, r1, r2};
    const int* cs[3] = {c0, c1, c2};
    const float* as[3] = {aj0, aj1, aj2};
    for (int s = 0; s < 3; ++s) {
        const int* __restrict__ r = rs[s];
        const int* __restrict__ c = cs[s];
        const float* __restrict__ aj = as[s];
        int* __restrict__ cur = cursor + s * N0;
        for (int e = lo + threadIdx.x; e < hi; e += 256) {
            int rr = r[e];
            if (rr < rlo || rr >= rhi) continue;
            int col = c[e];
            float sg = sigm(ai0[rr] + aj[col]);
            int pos = atomicAdd(&cur[rr], 1);
            uint2 v; v.x = (uint)col; v.y = __float_as_uint(sg);
            elist2[pos] = v;
        }
    }
}

// ---------------------------------------------------------------------------
// Aggregation: one wave per (set s, row r); 8 edges in flight per iteration
// (quarter-wave per edge x 2-deep unroll; each lane gathers 16B of the row).
// Fused: kvals[s][r] = agg[s][r] . wk + wkb
// ---------------------------------------------------------------------------
__launch_bounds__(256)
__global__ void agg_kernel(const ushort* __restrict__ xj0, const ushort* __restrict__ xj1,
                           const ushort* __restrict__ xj2,
                           const int* __restrict__ offs, const uint2* __restrict__ elist2,
                           const float* __restrict__ wk, const float* __restrict__ wkb,
                           int N0,
                           ushort* __restrict__ agg, float* __restrict__ kvals)
{
    int w = (blockIdx.x * blockDim.x + threadIdx.x) >> 6;
    int lane = threadIdx.x & 63;
    if (w >= 3 * N0) return;
    int s = w / N0;
    const ushort* xj = (s == 0) ? xj0 : ((s == 1) ? xj1 : xj2);

    int q = lane >> 4;         // quarter 0..3
    int ql = lane & 15;        // 16B chunk of row

    int beg = offs[w], end = offs[w + 1];
    float a0 = 0.f, a1 = 0.f, a2 = 0.f, a3 = 0.f;
    float a4 = 0.f, a5 = 0.f, a6 = 0.f, a7 = 0.f;
    for (int j = beg; j < end; j += 8) {
        int jA = j + q;
        int jB = j + 4 + q;
        int colA = 0, colB = 0;
        float sgA = 0.f, sgB = 0.f;
        if (jA < end) {
            uint2 es = elist2[jA];
            colA = (int)es.x; sgA = __uint_as_float(es.y);
        }
        if (jB < end) {
            uint2 es = elist2[jB];
            colB = (int)es.x; sgB = __uint_as_float(es.y);
        }
        uint4 pA = *(const uint4*)&xj[(size_t)colA * 128 + ql * 8];
        uint4 pB = *(const uint4*)&xj[(size_t)colB * 128 + ql * 8];
        a0 += sgA * lo16(pA.x); a1 += sgA * hi16(pA.x);
        a2 += sgA * lo16(pA.y); a3 += sgA * hi16(pA.y);
        a4 += sgA * lo16(pA.z); a5 += sgA * hi16(pA.z);
        a6 += sgA * lo16(pA.w); a7 += sgA * hi16(pA.w);
        a0 += sgB * lo16(pB.x); a1 += sgB * hi16(pB.x);
        a2 += sgB * lo16(pB.y); a3 += sgB * hi16(pB.y);
        a4 += sgB * lo16(pB.z); a5 += sgB * hi16(pB.z);
        a6 += sgB * lo16(pB.w); a7 += sgB * hi16(pB.w);
    }
    // combine the four quarters
    a0 += __shfl_xor(a0, 16); a0 += __shfl_xor(a0, 32);
    a1 += __shfl_xor(a1, 16); a1 += __shfl_xor(a1, 32);
    a2 += __shfl_xor(a2, 16); a2 += __shfl_xor(a2, 32);
    a3 += __shfl_xor(a3, 16); a3 += __shfl_xor(a3, 32);
    a4 += __shfl_xor(a4, 16); a4 += __shfl_xor(a4, 32);
    a5 += __shfl_xor(a5, 16); a5 += __shfl_xor(a5, 32);
    a6 += __shfl_xor(a6, 16); a6 += __shfl_xor(a6, 32);
    a7 += __shfl_xor(a7, 16); a7 += __shfl_xor(a7, 32);

    if (q == 0) {
        uint4 o;
        o.x = pack2(a0, a1); o.y = pack2(a2, a3);
        o.z = pack2(a4, a5); o.w = pack2(a6, a7);
        *(uint4*)&agg[(size_t)w * 128 + ql * 8] = o;
    }

    float4 wka = *(const float4*)&wk[ql * 8];
    float4 wkb4 = *(const float4*)&wk[ql * 8 + 4];
    float kp = a0 * wka.x + a1 * wka.y + a2 * wka.z + a3 * wka.w
             + a4 * wkb4.x + a5 * wkb4.y + a6 * wkb4.z + a7 * wkb4.w;
    #pragma unroll
    for (int m = 1; m < 16; m <<= 1) kp += __shfl_xor(kp, m);
    if (lane == 0) kvals[w] = kp + wkb[0];
}

// ---------------------------------------------------------------------------
// Fused mix + GEMM(wvwT) + LN1 -> bf16
// ---------------------------------------------------------------------------
__launch_bounds__(256)
__global__ void mixln_kernel(const float* __restrict__ x0, int N,
    const ushort* __restrict__ aggAll,
    const float* __restrict__ q, const float* __restrict__ kx0,
    const float* __restrict__ kvals,
    const ushort* __restrict__ WT, const float* __restrict__ bvec,
    const float* __restrict__ g, const float* __restrict__ beta,
    ushort* __restrict__ out)
{
    __shared__ ushort Wt[128][136];
    __shared__ ushort Xs[64][136];
    __shared__ float4 srow[64];
    const int tid = threadIdx.x;
    const int N0 = N;

    #pragma unroll
    for (int i = 0; i < 8; ++i) {
        int gi = tid + i * 256;
        int row = gi >> 4, c8 = (gi & 15) << 3;
        *(uint4*)&Wt[row][c8] = *(const uint4*)&WT[row * 128 + c8];
    }
    const int rowbase = blockIdx.x << 6;
    if (tid < 64) {
        int row = rowbase + tid;
        float4 sv = make_float4(0.f, 0.f, 0.f, 0.f);
        if (row < N) {
            float qv = q[row];
            sv.x = sigm(qv * kx0[row]);
            sv.y = sigm(qv * kvals[row]);
            sv.z = sigm(qv * kvals[N0 + row]);
            sv.w = sigm(qv * kvals[2 * N0 + row]);
        }
        srow[tid] = sv;
    }
    __syncthreads();

    #pragma unroll
    for (int i = 0; i < 4; ++i) {
        int gi = tid + i * 256;
        int r = gi >> 4;
        int c8 = (gi & 15) << 3;
        int grow = rowbase + r;
        uint4 v = make_uint4(0, 0, 0, 0);
        if (grow < N) {
            float4 sv = srow[r];
            float4 xa = *(const float4*)&x0[(size_t)grow * 128 + c8];
            float4 xb = *(const float4*)&x0[(size_t)grow * 128 + c8 + 4];
            uint4 g0 = *(const uint4*)&aggAll[(size_t)grow * 128 + c8];
            uint4 g1 = *(const uint4*)&aggAll[((size_t)N0 + grow) * 128 + c8];
            uint4 g2 = *(const uint4*)&aggAll[((size_t)2 * N0 + grow) * 128 + c8];
            float t0 = sv.x * xa.x + sv.y * lo16(g0.x) + sv.z * lo16(g1.x) + sv.w * lo16(g2.x);
            float t1 = sv.x * xa.y + sv.y * hi16(g0.x) + sv.z * hi16(g1.x) + sv.w * hi16(g2.x);
            float t2 = sv.x * xa.z + sv.y * lo16(g0.y) + sv.z * lo16(g1.y) + sv.w * lo16(g2.y);
            float t3 = sv.x * xa.w + sv.y * hi16(g0.y) + sv.z * hi16(g1.y) + sv.w * hi16(g2.y);
            float t4 = sv.x * xb.x + sv.y * lo16(g0.z) + sv.z * lo16(g1.z) + sv.w * lo16(g2.z);
            float t5 = sv.x * xb.y + sv.y * hi16(g0.z) + sv.z * hi16(g1.z) + sv.w * hi16(g2.z);
            float t6 = sv.x * xb.z + sv.y * lo16(g0.w) + sv.z * lo16(g1.w) + sv.w * lo16(g2.w);
            float t7 = sv.x * xb.w + sv.y * hi16(g0.w) + sv.z * hi16(g1.w) + sv.w * hi16(g2.w);
            v.x = pack2(t0, t1); v.y = pack2(t2, t3);
            v.z = pack2(t4, t5); v.w = pack2(t6, t7);
        }
        *(uint4*)&Xs[r][c8] = v;
    }
    __syncthreads();

    const int wv = tid >> 6, lane = tid & 63;
    const int c = lane & 15, blk = lane >> 4;

    float4v acc[8];
    #pragma unroll
    for (int n = 0; n < 8; ++n) acc[n] = (float4v){0.f, 0.f, 0.f, 0.f};
    #pragma unroll
    for (int kk = 0; kk < 4; ++kk) {
        short8v a = *(const short8v*)&Xs[wv * 16 + c][kk * 32 + blk * 8];
        #pragma unroll
        for (int n = 0; n < 8; ++n) {
            short8v bb = *(const short8v*)&Wt[n * 16 + c][kk * 32 + blk * 8];
            acc[n] = __builtin_amdgcn_mfma_f32_16x16x32_bf16(a, bb, acc[n], 0, 0, 0);
        }
    }

    float cf[4];
    #pragma unroll
    for (int i = 0; i < 4; ++i) {
        int rloc = wv * 16 + blk * 4 + i;
        float4 sv = srow[rloc];
        cf[i] = (sv.x + sv.y + sv.z + sv.w) * 0.25f;
    }

    float vals[8][4];
    float sum[4] = {0.f, 0.f, 0.f, 0.f}, sq[4] = {0.f, 0.f, 0.f, 0.f};
    #pragma unroll
    for (int n = 0; n < 8; ++n) {
        int col = n * 16 + c;
        float bc = bvec[col];
        #pragma unroll
        for (int i = 0; i < 4; ++i) {
            int grow = rowbase + wv * 16 + blk * 4 + i;
            float rv = (grow < N) ? x0[(size_t)grow * 128 + col] : 0.f;
            float v = acc[n][i] * 0.25f + cf[i] * bc + rv;
            vals[n][i] = v;
            sum[i] += v;
            sq[i] += v * v;
        }
    }
    #pragma unroll
    for (int m = 1; m < 16; m <<= 1)
        #pragma unroll
        for (int i = 0; i < 4; ++i) {
            sum[i] += __shfl_xor(sum[i], m);
            sq[i] += __shfl_xor(sq[i], m);
        }
    float mu[4], rs[4];
    #pragma unroll
    for (int i = 0; i < 4; ++i) {
        mu[i] = sum[i] * (1.0f / 128.0f);
        float var = sq[i] * (1.0f / 128.0f) - mu[i] * mu[i];
        rs[i] = rsqrtf(var + EPSF);
    }
    #pragma unroll
    for (int n = 0; n < 8; ++n) {
        int col = n * 16 + c;
        float gc = g[col], bc = beta[col];
        #pragma unroll
        for (int i = 0; i < 4; ++i) {
            int grow = rowbase + wv * 16 + blk * 4 + i;
            if (grow < N)
                out[(size_t)grow * 128 + col] = f2b((vals[n][i] - mu[i]) * rs[i] * gc + bc);
        }
    }
}

// ---------------------------------------------------------------------------
// Final: y = A@Wo + bo + A; out = LN(y) -> f32
// ---------------------------------------------------------------------------
__launch_bounds__(256)
__global__ void gemm_ln_kernel(const ushort* __restrict__ A, int N,
    const ushort* __restrict__ WT, const float* __restrict__ bvec,
    const float* __restrict__ g, const float* __restrict__ beta,
    float* __restrict__ outF)
{
    __shared__ ushort Wt[128][136];
    __shared__ ushort Xs[64][136];
    const int tid = threadIdx.x;

    #pragma unroll
    for (int i = 0; i < 8; ++i) {
        int gi = tid + i * 256;
        int row = gi >> 4, c8 = (gi & 15) << 3;
        *(uint4*)&Wt[row][c8] = *(const uint4*)&WT[row * 128 + c8];
    }
    const int rowbase = blockIdx.x << 6;
    #pragma unroll
    for (int i = 0; i < 4; ++i) {
        int gi = tid + i * 256;
        int r = gi >> 4;
        int c8 = (gi & 15) << 3;
        int grow = rowbase + r;
        uint4 v = make_uint4(0, 0, 0, 0);
        if (grow < N) v = *(const uint4*)&A[(size_t)grow * 128 + c8];
        *(uint4*)&Xs[r][c8] = v;
    }
    __syncthreads();

    const int wv = tid >> 6, lane = tid & 63;
    const int c = lane & 15, blk = lane >> 4;

    float4v acc[8];
    #pragma unroll
    for (int n = 0; n < 8; ++n) acc[n] = (float4v){0.f, 0.f, 0.f, 0.f};
    #pragma unroll
    for (int kk = 0; kk < 4; ++kk) {
        short8v a = *(const short8v*)&Xs[wv * 16 + c][kk * 32 + blk * 8];
        #pragma unroll
        for (int n = 0; n < 8; ++n) {
            short8v bb = *(const short8v*)&Wt[n * 16 + c][kk * 32 + blk * 8];
            acc[n] = __builtin_amdgcn_mfma_f32_16x16x32_bf16(a, bb, acc[n], 0, 0, 0);
        }
    }

    float vals[8][4];
    float sum[4] = {0.f, 0.f, 0.f, 0.f}, sq[4] = {0.f, 0.f, 0.f, 0.f};
    #pragma unroll
    for (int n = 0; n < 8; ++n) {
        int col = n * 16 + c;
        float bc = bvec[col];
        #pragma unroll
        for (int i = 0; i < 4; ++i) {
            int rloc = wv * 16 + blk * 4 + i;
            float rv = b2f(Xs[rloc][col]);   // resid = A (bf16) from LDS
            float v = acc[n][i] + bc + rv;
            vals[n][i] = v;
            sum[i] += v;
            sq[i] += v * v;
        }
    }
    #pragma unroll
    for (int m = 1; m < 16; m <<= 1)
        #pragma unroll
        for (int i = 0; i < 4; ++i) {
            sum[i] += __shfl_xor(sum[i], m);
            sq[i] += __shfl_xor(sq[i], m);
        }
    float mu[4], rs[4];
    #pragma unroll
    for (int i = 0; i < 4; ++i) {
        mu[i] = sum[i] * (1.0f / 128.0f);
        float var = sq[i] * (1.0f / 128.0f) - mu[i] * mu[i];
        rs[i] = rsqrtf(var + EPSF);
    }
    #pragma unroll
    for (int n = 0; n < 8; ++n) {
        int col = n * 16 + c;
        float gc = g[col], bc = beta[col];
        #pragma unroll
        for (int i = 0; i < 4; ++i) {
            int grow = rowbase + wv * 16 + blk * 4 + i;
            if (grow < N)
                outF[(size_t)grow * 128 + col] = (vals[n][i] - mu[i]) * rs[i] * gc + bc;
        }
    }
}

// ---------------------------------------------------------------------------
extern "C" void kernel_launch(void* const* d_in, const int* in_sizes, int n_in,
                              void* d_out, int out_size, void* d_ws, size_t ws_size,
                              hipStream_t stream)
{
    const float* x0 = (const float*)d_in[0];
    const float* x1 = (const float*)d_in[1];
    const float* x2 = (const float*)d_in[2];
    const int* rows0 = (const int*)d_in[3];
    const int* cols0 = (const int*)d_in[4];
    const int* rows1 = (const int*)d_in[5];
    const int* cols1 = (const int*)d_in[6];
    const int* rows2 = (const int*)d_in[7];
    const int* cols2 = (const int*)d_in[8];
    const float* W1 = (const float*)d_in[9];   const float* b1 = (const float*)d_in[10];
    const float* W2 = (const float*)d_in[11];  const float* b2 = (const float*)d_in[12];
    const float* W3 = (const float*)d_in[13];  const float* b3 = (const float*)d_in[14];
    const float* W4 = (const float*)d_in[15];  const float* b4 = (const float*)d_in[16];
    const float* a1w = (const float*)d_in[17]; const float* a1b = (const float*)d_in[18];
    const float* a2w = (const float*)d_in[19]; const float* a2b = (const float*)d_in[20];
    const float* a3w = (const float*)d_in[21]; const float* a3b = (const float*)d_in[22];
    const float* a4w = (const float*)d_in[23]; const float* a4b = (const float*)d_in[24];
    const float* wqw = (const float*)d_in[25]; const float* wqb = (const float*)d_in[26];
    const float* wkw = (const float*)d_in[27]; const float* wkb = (const float*)d_in[28];
    const float* wvw = (const float*)d_in[29]; const float* wvb = (const float*)d_in[30];
    const float* Wo  = (const float*)d_in[31]; const float* bo = (const float*)d_in[32];
    const float* ln1g = (const float*)d_in[33]; const float* ln1b = (const float*)d_in[34];
    const float* ln2g = (const float*)d_in[35]; const float* ln2b = (const float*)d_in[36];

    const int N0 = in_sizes[0] / 128;
    const int N1 = in_sizes[1] / 128;
    const int N2 = in_sizes[2] / 128;
    const int E  = in_sizes[3];
    const int M  = 3 * N0;

    char* p = (char*)d_ws;
    auto walloc = [&](size_t bytes) -> void* {
        void* r = (void*)p;
        p += (bytes + 255) & ~(size_t)255;
        return r;
    };
    ushort* agg  = (ushort*)walloc((size_t)3 * N0 * 128 * 2);
    ushort* xj0  = (ushort*)walloc((size_t)N0 * 128 * 2);
    ushort* xj1  = (ushort*)walloc((size_t)N1 * 128 * 2);
    ushort* xj2  = (ushort*)walloc((size_t)N2 * 128 * 2);
    float* ai0   = (float*)walloc((size_t)N0 * 4);
    float* aj0   = (float*)walloc((size_t)N0 * 4);
    float* aj1   = (float*)walloc((size_t)N1 * 4);
    float* aj2   = (float*)walloc((size_t)N2 * 4);
    float* qv    = (float*)walloc((size_t)N0 * 4);
    float* kx0   = (float*)walloc((size_t)N0 * 4);
    float* kvals = (float*)walloc((size_t)3 * N0 * 4);
    int* deg     = (int*)walloc((size_t)M * 4);
    int* offs    = (int*)walloc(((size_t)M + 1) * 4);
    int* cursor  = (int*)walloc((size_t)M * 4);
    int* bsum    = (int*)walloc(1024 * 4);
    ushort* wtb  = (ushort*)walloc((size_t)6 * 16384 * 2);   // 6 transposed bf16 weights
    uint2* elist2 = (uint2*)walloc((size_t)3 * E * 8);
    ushort* u = (N1 >= N0) ? xj1 : (ushort*)walloc((size_t)N0 * 128 * 2);

    hipMemsetAsync(deg, 0, (size_t)M * 4, stream);

    // one-time weight transpose+convert
    prep_weights<<<6, 256, 0, stream>>>(W1, W2, W3, W4, wvw, Wo, wtb);
    const ushort* W1T = wtb;
    const ushort* W2T = wtb + 16384;
    const ushort* W3T = wtb + 2 * 16384;
    const ushort* W4T = wtb + 3 * 16384;
    const ushort* WvT = wtb + 4 * 16384;
    const ushort* WoT = wtb + 5 * 16384;

    // combined transforms (one launch)
    int nb0 = (N0 + 63) / 64, nb1 = (N1 + 63) / 64, nb2 = (N2 + 63) / 64;
    TSegs P;
    P.s[0] = {x0, W1T, b1, a1w, a1b, nullptr, ai0, N0, 0};
    P.s[1] = {x0, W2T, b2, a2w, a2b, xj0, aj0, N0, nb0};
    P.s[2] = {x1, W3T, b3, a3w, a3b, xj1, aj1, N1, 2 * nb0};
    P.s[3] = {x2, W4T, b4, a4w, a4b, xj2, aj2, N2, 2 * nb0 + nb1};
    transform4_kernel<<<2 * nb0 + nb1 + nb2, 256, 0, stream>>>(
        P, wqw, wqb, wkw, wkb, qv, kx0);

    // CSR build — XCD-local partitioned scatter, high-occupancy grid
    const int nchunk = 448;                         // blocks per partition
    degree_kernel<<<NPART * nchunk, 256, 0, stream>>>(rows0, rows1, rows2, E, N0,
                                                      nchunk, deg);
    int nb = (M + 1023) / 1024;
    scan_phase1<<<nb, 256, 0, stream>>>(deg, M, bsum);
    scan_phase2<<<1, 1024, 0, stream>>>(bsum, nb, M, offs);
    scan_phase3<<<nb, 256, 0, stream>>>(deg, M, bsum, offs, cursor);
    fill_kernel<<<NPART * nchunk, 256, 0, stream>>>(rows0, rows1, rows2,
                                                    cols0, cols1, cols2, E, N0, nchunk,
                                                    ai0, aj0, aj1, aj2, cursor, elist2);

    // aggregation (one wave per (s,row), 8 edges in flight)
    int aggblocks = (3 * N0 + 3) / 4;
    agg_kernel<<<aggblocks, 256, 0, stream>>>(
        xj0, xj1, xj2, offs, elist2, wkw, wkb, N0, agg, kvals);

    // fused mix + GEMM(wvw) + LN1 -> u (bf16)
    mixln_kernel<<<(N0 + 63) / 64, 256, 0, stream>>>(
        x0, N0, agg, qv, kx0, kvals, WvT, wvb, ln1g, ln1b, u);

    // u@Wo + bo + u -> LN2 -> out (f32)
    gemm_ln_kernel<<<(N0 + 63) / 64, 256, 0, stream>>>(
        u, N0, WoT, bo, ln2g, ln2b, (float*)d_out);
}